// Round 5
// baseline (1221.223 us; speedup 1.0000x reference)
//
#include <hip/hip_runtime.h>

#define IN_DIM 384
#define HID    128
#define NPB    256            // nodes per bucket (dstLocal fits in 8 bits)
#define SL_NW  16             // nodes per wave in slice-agg kernels

typedef _Float16 half8 __attribute__((ext_vector_type(8)));
typedef _Float16 half2v __attribute__((ext_vector_type(2)));
typedef float floatx4 __attribute__((ext_vector_type(4)));

// ---------------- utility ----------------
__global__ void zero_i32(int* __restrict__ p, int n) {
  int i = blockIdx.x * 256 + threadIdx.x;
  if (i < n) p[i] = 0;
}

// ---------------- phase 0: coarse bucket histogram (LDS hist, 1 atomic/block/bucket) ----
__global__ __launch_bounds__(256) void bucket_count(
    const int* __restrict__ dst, int E, int nB, int* __restrict__ bucketCnt) {
  __shared__ int hist[391];
  const int t = threadIdx.x;
  const int b0 = blockIdx.x * 8192;
  for (int i = t; i < nB; i += 256) hist[i] = 0;
  __syncthreads();
#pragma unroll
  for (int i = 0; i < 32; ++i) {
    int e = b0 + i * 256 + t;
    if (e < E) atomicAdd(&hist[dst[e] >> 8], 1);
  }
  __syncthreads();
  for (int i = t; i < nB; i += 256) {
    int h = hist[i];
    if (h) atomicAdd(&bucketCnt[i], h);
  }
}

// ---------------- bucket scan: offsets for 391 buckets (single block) ----------------
__global__ void scan_buckets(const int* __restrict__ bucketCnt, int nB, int E, int N,
                             int* __restrict__ bucketBase, int* __restrict__ bCur,
                             int* __restrict__ rs) {
  __shared__ int s[512];
  const int t = threadIdx.x;
  int v = (t < nB) ? bucketCnt[t] : 0;
  s[t] = v;
  __syncthreads();
  for (int off = 1; off < 512; off <<= 1) {
    int y = (t >= off) ? s[t - off] : 0;
    __syncthreads();
    s[t] += y;
    __syncthreads();
  }
  int excl = s[t] - v;
  if (t < nB) {
    bucketBase[t] = excl;
    bCur[t] = excl;
  }
  if (t == nB) bucketBase[nB] = excl;  // == E
  if (t == 0) rs[N] = E;
}

// ---------------- phase 1: partition edges into coarse buckets ----------------
// 8192 edges/block; packed value = (dstLocal << 17) | src  (src < 2^17, dstLocal < 256)
__global__ __launch_bounds__(256) void partition_kernel(
    const int* __restrict__ src, const int* __restrict__ dst, int E, int nB,
    int* __restrict__ bucketCursor, unsigned* __restrict__ bucketData) {
  __shared__ int hist[391];
  __shared__ int gbase[391];
  const int t = threadIdx.x;
  const int b0 = blockIdx.x * 8192;

  for (int i = t; i < nB; i += 256) hist[i] = 0;
  __syncthreads();
#pragma unroll
  for (int i = 0; i < 32; ++i) {
    int e = b0 + i * 256 + t;
    if (e < E) atomicAdd(&hist[dst[e] >> 8], 1);
  }
  __syncthreads();
  for (int i = t; i < nB; i += 256) {
    int h = hist[i];
    gbase[i] = h ? atomicAdd(&bucketCursor[i], h) : 0;
    hist[i] = 0;
  }
  __syncthreads();
#pragma unroll
  for (int i = 0; i < 32; ++i) {
    int e = b0 + i * 256 + t;
    if (e < E) {
      int d = dst[e];
      int b = d >> 8;
      int r = atomicAdd(&hist[b], 1);
      bucketData[gbase[b] + r] = ((unsigned)(d & 255) << 17) | (unsigned)src[e];
    }
  }
}

// ---------------- phase 2: per-bucket node histogram + scan + scatter ----------------
__global__ __launch_bounds__(256) void node_sort2(
    const unsigned* __restrict__ bucketData, const int* __restrict__ bucketBase,
    int N, int* __restrict__ sorted_src, int* __restrict__ rs) {
  __shared__ int hist[NPB];
  __shared__ int s[NPB];
  __shared__ int cur[NPB];
  const int b = blockIdx.x;
  const int t = threadIdx.x;
  const int start = bucketBase[b];
  const int end = bucketBase[b + 1];
  hist[t] = 0;
  __syncthreads();
  for (int e = start + t; e < end; e += 256) atomicAdd(&hist[bucketData[e] >> 17], 1);
  __syncthreads();
  int v = hist[t];
  s[t] = v;
  __syncthreads();
  for (int off = 1; off < 256; off <<= 1) {
    int y = (t >= off) ? s[t - off] : 0;
    __syncthreads();
    s[t] += y;
    __syncthreads();
  }
  int excl = s[t] - v;
  const int node = b * NPB + t;
  if (node <= N) rs[node] = start + excl;
  cur[t] = start + excl;
  __syncthreads();
  for (int e = start + t; e < end; e += 256) {
    unsigned d = bucketData[e];
    int p = atomicAdd(&cur[d >> 17], 1);
    sorted_src[p] = (int)(d & 0x1FFFF);
  }
}

// ---------------- weight pack: W[K][128] fp32 -> per-lane MFMA B-fragment order ----------------
__global__ void pack_w(const float* __restrict__ W, _Float16* __restrict__ Bp,
                       int tnBase) {
  const int tn = blockIdx.x;
  const int ks = blockIdx.y;
  const int KS = gridDim.y;
  const int lane = threadIdx.x;
  const int n = tn * 16 + (lane & 15);
  const int kb = ks * 32 + (lane >> 4) * 8;
  half8 v;
#pragma unroll
  for (int j = 0; j < 8; ++j) v[j] = (_Float16)W[(size_t)(kb + j) * HID + n];
  *(half8*)(Bp + (((size_t)(tnBase + tn) * KS + ks) * 64 + lane) * 8) = v;
}

// ---------------- fp16 MFMA GEMM: C[M x 256] = A[M x K] @ [Bl | Br] ----------------
__global__ __launch_bounds__(512) void gemm_f16(
    const float* __restrict__ A32, const _Float16* __restrict__ A16,
    int M, int K,
    const _Float16* __restrict__ Bp,
    _Float16* __restrict__ C) {
  __shared__ _Float16 As[128][40];

  const int KS = K >> 5;
  const int tid = threadIdx.x;
  const int lane = tid & 63;
  const int wid = tid >> 6;
  const int quad = lane >> 4;
  const int lm = lane & 15;
  const int row0 = (wid & 1) * 64;
  const int ct0 = (wid >> 1) * 4;
  const int blockRow = blockIdx.x * 128;

  const int srow = tid >> 2;
  const int scol = (tid & 3) * 8;

  floatx4 acc[16];
#pragma unroll
  for (int i = 0; i < 16; ++i) {
    acc[i][0] = 0.f; acc[i][1] = 0.f; acc[i][2] = 0.f; acc[i][3] = 0.f;
  }

  for (int ks = 0; ks < KS; ++ks) {
    const int gr = blockRow + srow;
    half8 hv;
    if (A32) {
      float4 f0 = make_float4(0.f, 0.f, 0.f, 0.f), f1 = f0;
      if (gr < M) {
        const float* p = A32 + (size_t)gr * K + ks * 32 + scol;
        f0 = *(const float4*)p;
        f1 = *(const float4*)(p + 4);
      }
      hv[0] = (_Float16)f0.x; hv[1] = (_Float16)f0.y;
      hv[2] = (_Float16)f0.z; hv[3] = (_Float16)f0.w;
      hv[4] = (_Float16)f1.x; hv[5] = (_Float16)f1.y;
      hv[6] = (_Float16)f1.z; hv[7] = (_Float16)f1.w;
    } else {
      if (gr < M) {
        hv = *(const half8*)(A16 + (size_t)gr * K + ks * 32 + scol);
      } else {
#pragma unroll
        for (int j = 0; j < 8; ++j) hv[j] = (_Float16)0.f;
      }
    }
    __syncthreads();
    *(half8*)&As[srow][scol] = hv;
    __syncthreads();

    half8 af[4], bf[4];
#pragma unroll
    for (int rt = 0; rt < 4; ++rt)
      af[rt] = *(const half8*)&As[row0 + rt * 16 + lm][quad * 8];
#pragma unroll
    for (int ct = 0; ct < 4; ++ct) {
      const int tn = ct0 + ct;
      bf[ct] = *(const half8*)(Bp + (((size_t)tn * KS + ks) * 64 + lane) * 8);
    }
#pragma unroll
    for (int rt = 0; rt < 4; ++rt)
#pragma unroll
      for (int ct = 0; ct < 4; ++ct)
        acc[rt * 4 + ct] =
            __builtin_amdgcn_mfma_f32_16x16x32_f16(af[rt], bf[ct], acc[rt * 4 + ct], 0, 0, 0);
  }

#pragma unroll
  for (int rt = 0; rt < 4; ++rt) {
#pragma unroll
    for (int r = 0; r < 4; ++r) {
      const int gm = blockRow + row0 + rt * 16 + quad * 4 + r;
      if (gm < M) {
#pragma unroll
        for (int ct = 0; ct < 4; ++ct) {
          const int col = (ct0 + ct) * 16 + lm;
          C[(size_t)gm * 256 + col] = (_Float16)acc[rt * 4 + ct][r];
        }
      }
    }
  }
}

// ---------------- helpers ----------------
__device__ inline float2 upk(unsigned u) {
  union { unsigned v; _Float16 h[2]; } c; c.v = u;
  return make_float2((float)c.h[0], (float)c.h[1]);
}
__device__ inline half2v as_h2(unsigned u) {
  union { unsigned v; half2v h; } c; c.v = u;
  return c.h;
}
__device__ inline unsigned as_u32(half2v h) {
  union { half2v h; unsigned v; } c; c.h = h;
  return c.v;
}

// ---------------- layer-1 slice aggregation: slice = blockIdx & 7 -> XCD affinity ----
// Per slice the gather working set is N*32B = 3.2MB (L2-resident per XCD).
// Wave: 8 cols x 8 edge-slots; fp16 packed accumulate, 2x unrolled MLP.
__global__ __launch_bounds__(256) void agg_relu_slice(
    const unsigned* __restrict__ yzu, const int* __restrict__ sorted_src,
    const int* __restrict__ rs, const float* __restrict__ bias,
    unsigned* __restrict__ h1u, int N) {
  const int slice = blockIdx.x & 7;
  const int chunk = blockIdx.x >> 3;
  const int w = threadIdx.x >> 6;
  const int l = threadIdx.x & 63;
  const int c = l & 7;
  const int esl = l >> 3;
  const int cp = slice * 8 + c;   // u32 column 0..63
  const int n0 = (chunk * 4 + w) * SL_NW;

  for (int i = 0; i < SL_NW; ++i) {
    const int node = n0 + i;
    if (node >= N) return;
    const int start = rs[node];
    const int end = rs[node + 1];
    half2v a0; a0[0] = (_Float16)0.f; a0[1] = (_Float16)0.f;
    half2v a1 = a0;
    int k = start + esl;
    for (; k + 8 < end; k += 16) {
      int s0 = sorted_src[k];
      int s1 = sorted_src[k + 8];
      unsigned v0 = yzu[(size_t)s0 * 128 + cp];
      unsigned v1 = yzu[(size_t)s1 * 128 + cp];
      a0 += as_h2(v0);
      a1 += as_h2(v1);
    }
    if (k < end) {
      int s = sorted_src[k];
      a0 += as_h2(yzu[(size_t)s * 128 + cp]);
    }
    a0 += a1;
    // reduce over edge-slots (xor 8,16,32)
#pragma unroll
    for (int off = 8; off < 64; off <<= 1)
      a0 += as_h2((unsigned)__shfl_xor((int)as_u32(a0), off, 64));
    if (esl == 0) {
      const int deg = end - start;
      const float inv = 1.f / (float)max(deg, 1);
      float2 z = upk(yzu[(size_t)node * 128 + 64 + cp]);
      float vx = fmaxf((float)a0[0] * inv + bias[2 * cp] + z.x, 0.f);
      float vy = fmaxf((float)a0[1] * inv + bias[2 * cp + 1] + z.y, 0.f);
      union { unsigned v; _Float16 h[2]; } o;
      o.h[0] = (_Float16)vx; o.h[1] = (_Float16)vy;
      h1u[(size_t)node * 64 + cp] = o.v;
    }
  }
}

// ---------------- layer-2 slice aggregation + partial scorer projection ----------------
// part[slice*N + node] = pa partial, part[(8+slice)*N + node] = pb partial.
__global__ __launch_bounds__(256) void agg_score_slice(
    const unsigned* __restrict__ yzu, const int* __restrict__ sorted_src,
    const int* __restrict__ rs, const float* __restrict__ bias,
    const float* __restrict__ Wlin, float* __restrict__ part, int N) {
  const int slice = blockIdx.x & 7;
  const int chunk = blockIdx.x >> 3;
  const int w = threadIdx.x >> 6;
  const int l = threadIdx.x & 63;
  const int c = l & 7;
  const int esl = l >> 3;
  const int cp = slice * 8 + c;
  const int n0 = (chunk * 4 + w) * SL_NW;

  for (int i = 0; i < SL_NW; ++i) {
    const int node = n0 + i;
    if (node >= N) return;
    const int start = rs[node];
    const int end = rs[node + 1];
    half2v a0; a0[0] = (_Float16)0.f; a0[1] = (_Float16)0.f;
    half2v a1 = a0;
    int k = start + esl;
    for (; k + 8 < end; k += 16) {
      int s0 = sorted_src[k];
      int s1 = sorted_src[k + 8];
      unsigned v0 = yzu[(size_t)s0 * 128 + cp];
      unsigned v1 = yzu[(size_t)s1 * 128 + cp];
      a0 += as_h2(v0);
      a1 += as_h2(v1);
    }
    if (k < end) {
      int s = sorted_src[k];
      a0 += as_h2(yzu[(size_t)s * 128 + cp]);
    }
    a0 += a1;
#pragma unroll
    for (int off = 8; off < 64; off <<= 1)
      a0 += as_h2((unsigned)__shfl_xor((int)as_u32(a0), off, 64));
    // all lanes now hold the column-pair total for their c
    const int deg = end - start;
    const float inv = 1.f / (float)max(deg, 1);
    float2 z = upk(yzu[(size_t)node * 128 + 64 + cp]);
    float hx = (float)a0[0] * inv + bias[2 * cp] + z.x;
    float hy = (float)a0[1] * inv + bias[2 * cp + 1] + z.y;
    float pa = hx * Wlin[2 * cp] + hy * Wlin[2 * cp + 1];
    float pb = hx * Wlin[128 + 2 * cp] + hy * Wlin[129 + 2 * cp];
    // reduce over c (xor 1,2,4)
#pragma unroll
    for (int off = 1; off < 8; off <<= 1) {
      pa += __shfl_xor(pa, off, 64);
      pb += __shfl_xor(pb, off, 64);
    }
    if (l == 0) {
      part[(size_t)slice * N + node] = pa;
      part[(size_t)(8 + slice) * N + node] = pb;
    }
  }
}

// ---------------- cross-slice score reduction ----------------
__global__ void reduce_sab(const float* __restrict__ part, float* __restrict__ sa,
                           float* __restrict__ sb, int N) {
  int n = blockIdx.x * 256 + threadIdx.x;
  if (n < N) {
    float a = 0.f, b = 0.f;
#pragma unroll
    for (int s = 0; s < 8; ++s) {
      a += part[(size_t)s * N + n];
      b += part[(size_t)(8 + s) * N + n];
    }
    sa[n] = a;
    sb[n] = b;
  }
}

// ---------------- edge scoring: out[e] = s_a[i] + s_b[j] + b ----------------
__global__ void score_kernel(const int* __restrict__ idx, int E,
                             const float* __restrict__ sa, const float* __restrict__ sb,
                             const float* __restrict__ blin, float* __restrict__ out) {
  int e = blockIdx.x * 256 + threadIdx.x;
  if (e < E) out[e] = sa[idx[e]] + sb[idx[E + e]] + blin[0];
}

extern "C" void kernel_launch(void* const* d_in, const int* in_sizes, int n_in,
                              void* d_out, int out_size, void* d_ws, size_t ws_size,
                              hipStream_t stream) {
  (void)n_in; (void)out_size; (void)ws_size;
  const float* x    = (const float*)d_in[0];
  const int*   ei   = (const int*)d_in[1];
  const int*   pos  = (const int*)d_in[2];
  const int*   neg  = (const int*)d_in[3];
  const float* Wl1  = (const float*)d_in[4];
  const float* bl1  = (const float*)d_in[5];
  const float* Wr1  = (const float*)d_in[6];
  const float* Wl2  = (const float*)d_in[7];
  const float* bl2  = (const float*)d_in[8];
  const float* Wr2  = (const float*)d_in[9];
  const float* Wlin = (const float*)d_in[10];
  const float* blin = (const float*)d_in[11];

  const int N  = in_sizes[0] / IN_DIM;  // 100000
  const int E  = in_sizes[1] / 2;       // 3200000
  const int Ep = in_sizes[2] / 2;       // 500000
  const int En = in_sizes[3] / 2;       // 500000
  const int* e_src = ei;
  const int* e_dst = ei + E;

  char* ws = (char*)d_ws;
  size_t off = 0;
  auto carve = [&](size_t bytes) -> char* {
    char* p = ws + off;
    off += (bytes + 255) & ~(size_t)255;
    return p;
  };
  const int nB = (N + NPB - 1) / NPB;   // 391 buckets
  const int KS1 = IN_DIM / 32;          // 12
  const int KS2 = HID / 32;             // 4

  int*      rs     = (int*)carve((size_t)(N + 256) * 4);
  int*      bCnt   = (int*)carve(512 * 4);
  int*      bBase  = (int*)carve(512 * 4);
  int*      bCur   = (int*)carve(512 * 4);
  unsigned* bData  = (unsigned*)carve((size_t)E * 4);
  int*      sorted = (int*)carve((size_t)E * 4);
  float*    sa     = (float*)carve((size_t)N * 4);
  float*    sb     = (float*)carve((size_t)N * 4);
  float*    part   = (float*)carve((size_t)16 * N * 4);
  _Float16* Bp1    = (_Float16*)carve((size_t)16 * KS1 * 64 * 8 * 2);
  _Float16* Bp2    = (_Float16*)carve((size_t)16 * KS2 * 64 * 8 * 2);
  _Float16* yz     = (_Float16*)carve((size_t)N * 256 * 2);
  _Float16* h1     = (_Float16*)carve((size_t)N * 128 * 2);

  const int gemmBlocks = (N + 127) / 128;
  const int partBlocks = (E + 8191) / 8192;  // 391
  const int sliceChunks = (N + 4 * SL_NW - 1) / (4 * SL_NW);  // 1563
  const int sliceGrid = sliceChunks * 8;

  // CSR build (no per-node global atomics)
  hipLaunchKernelGGL(zero_i32, dim3(2), dim3(256), 0, stream, bCnt, 512);
  hipLaunchKernelGGL(bucket_count, dim3(partBlocks), dim3(256), 0, stream,
                     e_dst, E, nB, bCnt);
  hipLaunchKernelGGL(scan_buckets, dim3(1), dim3(512), 0, stream,
                     bCnt, nB, E, N, bBase, bCur, rs);
  hipLaunchKernelGGL(partition_kernel, dim3(partBlocks), dim3(256), 0, stream,
                     e_src, e_dst, E, nB, bCur, bData);
  hipLaunchKernelGGL(node_sort2, dim3(nB), dim3(256), 0, stream,
                     bData, bBase, N, sorted, rs);

  // weight packing (tiny)
  hipLaunchKernelGGL(pack_w, dim3(8, KS1), dim3(64), 0, stream, Wl1, Bp1, 0);
  hipLaunchKernelGGL(pack_w, dim3(8, KS1), dim3(64), 0, stream, Wr1, Bp1, 8);
  hipLaunchKernelGGL(pack_w, dim3(8, KS2), dim3(64), 0, stream, Wl2, Bp2, 0);
  hipLaunchKernelGGL(pack_w, dim3(8, KS2), dim3(64), 0, stream, Wr2, Bp2, 8);

  // layer 1
  hipLaunchKernelGGL(gemm_f16, dim3(gemmBlocks), dim3(512), 0, stream,
                     x, (const _Float16*)nullptr, N, IN_DIM, Bp1, yz);
  hipLaunchKernelGGL(agg_relu_slice, dim3(sliceGrid), dim3(256), 0, stream,
                     (const unsigned*)yz, sorted, rs, bl1, (unsigned*)h1, N);
  // layer 2
  hipLaunchKernelGGL(gemm_f16, dim3(gemmBlocks), dim3(512), 0, stream,
                     (const float*)nullptr, h1, N, HID, Bp2, yz);
  hipLaunchKernelGGL(agg_score_slice, dim3(sliceGrid), dim3(256), 0, stream,
                     (const unsigned*)yz, sorted, rs, bl2, Wlin, part, N);
  hipLaunchKernelGGL(reduce_sab, dim3((N + 255) / 256), dim3(256), 0, stream,
                     part, sa, sb, N);

  // scoring
  float* out = (float*)d_out;
  hipLaunchKernelGGL(score_kernel, dim3((Ep + 255) / 256), dim3(256), 0, stream,
                     pos, Ep, sa, sb, blin, out);
  hipLaunchKernelGGL(score_kernel, dim3((En + 255) / 256), dim3(256), 0, stream,
                     neg, En, sa, sb, blin, out + Ep);
}

// Round 6
// 637.573 us; speedup vs baseline: 1.9154x; 1.9154x over previous
//
#include <hip/hip_runtime.h>

#define IN_DIM 384
#define HID    128
#define NPB    256            // nodes per bucket (dstLocal fits in 8 bits)

typedef _Float16 half8 __attribute__((ext_vector_type(8)));
typedef _Float16 half2v __attribute__((ext_vector_type(2)));
typedef float floatx4 __attribute__((ext_vector_type(4)));

// ---------------- utility ----------------
__global__ void zero_i32(int* __restrict__ p, int n) {
  int i = blockIdx.x * 256 + threadIdx.x;
  if (i < n) p[i] = 0;
}

// ---------------- phase 0: coarse bucket histogram (LDS hist, 1 atomic/block/bucket) ----
__global__ __launch_bounds__(256) void bucket_count(
    const int* __restrict__ dst, int E, int nB, int* __restrict__ bucketCnt) {
  __shared__ int hist[391];
  const int t = threadIdx.x;
  const int b0 = blockIdx.x * 8192;
  for (int i = t; i < nB; i += 256) hist[i] = 0;
  __syncthreads();
#pragma unroll
  for (int i = 0; i < 32; ++i) {
    int e = b0 + i * 256 + t;
    if (e < E) atomicAdd(&hist[dst[e] >> 8], 1);
  }
  __syncthreads();
  for (int i = t; i < nB; i += 256) {
    int h = hist[i];
    if (h) atomicAdd(&bucketCnt[i], h);
  }
}

// ---------------- bucket scan: offsets for 391 buckets (single block) ----------------
__global__ void scan_buckets(const int* __restrict__ bucketCnt, int nB, int E, int N,
                             int* __restrict__ bucketBase, int* __restrict__ bCur,
                             int* __restrict__ rs) {
  __shared__ int s[512];
  const int t = threadIdx.x;
  int v = (t < nB) ? bucketCnt[t] : 0;
  s[t] = v;
  __syncthreads();
  for (int off = 1; off < 512; off <<= 1) {
    int y = (t >= off) ? s[t - off] : 0;
    __syncthreads();
    s[t] += y;
    __syncthreads();
  }
  int excl = s[t] - v;
  if (t < nB) {
    bucketBase[t] = excl;
    bCur[t] = excl;
  }
  if (t == nB) bucketBase[nB] = excl;  // == E
  if (t == 0) rs[N] = E;
}

// ---------------- phase 1: partition edges into coarse buckets ----------------
// 8192 edges/block; packed value = (dstLocal << 17) | src  (src < 2^17, dstLocal < 256)
__global__ __launch_bounds__(256) void partition_kernel(
    const int* __restrict__ src, const int* __restrict__ dst, int E, int nB,
    int* __restrict__ bucketCursor, unsigned* __restrict__ bucketData) {
  __shared__ int hist[391];
  __shared__ int gbase[391];
  const int t = threadIdx.x;
  const int b0 = blockIdx.x * 8192;

  for (int i = t; i < nB; i += 256) hist[i] = 0;
  __syncthreads();
#pragma unroll
  for (int i = 0; i < 32; ++i) {
    int e = b0 + i * 256 + t;
    if (e < E) atomicAdd(&hist[dst[e] >> 8], 1);
  }
  __syncthreads();
  for (int i = t; i < nB; i += 256) {
    int h = hist[i];
    gbase[i] = h ? atomicAdd(&bucketCursor[i], h) : 0;
    hist[i] = 0;
  }
  __syncthreads();
#pragma unroll
  for (int i = 0; i < 32; ++i) {
    int e = b0 + i * 256 + t;
    if (e < E) {
      int d = dst[e];
      int b = d >> 8;
      int r = atomicAdd(&hist[b], 1);
      bucketData[gbase[b] + r] = ((unsigned)(d & 255) << 17) | (unsigned)src[e];
    }
  }
}

// ---------------- phase 2: per-bucket node histogram + scan + scatter ----------------
__global__ __launch_bounds__(256) void node_sort2(
    const unsigned* __restrict__ bucketData, const int* __restrict__ bucketBase,
    int N, int* __restrict__ sorted_src, int* __restrict__ rs) {
  __shared__ int hist[NPB];
  __shared__ int s[NPB];
  __shared__ int cur[NPB];
  const int b = blockIdx.x;
  const int t = threadIdx.x;
  const int start = bucketBase[b];
  const int end = bucketBase[b + 1];
  hist[t] = 0;
  __syncthreads();
  for (int e = start + t; e < end; e += 256) atomicAdd(&hist[bucketData[e] >> 17], 1);
  __syncthreads();
  int v = hist[t];
  s[t] = v;
  __syncthreads();
  for (int off = 1; off < 256; off <<= 1) {
    int y = (t >= off) ? s[t - off] : 0;
    __syncthreads();
    s[t] += y;
    __syncthreads();
  }
  int excl = s[t] - v;
  const int node = b * NPB + t;
  if (node <= N) rs[node] = start + excl;
  cur[t] = start + excl;
  __syncthreads();
  for (int e = start + t; e < end; e += 256) {
    unsigned d = bucketData[e];
    int p = atomicAdd(&cur[d >> 17], 1);
    sorted_src[p] = (int)(d & 0x1FFFF);
  }
}

// ---------------- weight pack: W[K][128] fp32 -> per-lane MFMA B-fragment order ----------------
__global__ void pack_w(const float* __restrict__ W, _Float16* __restrict__ Bp,
                       int tnBase) {
  const int tn = blockIdx.x;
  const int ks = blockIdx.y;
  const int KS = gridDim.y;
  const int lane = threadIdx.x;
  const int n = tn * 16 + (lane & 15);
  const int kb = ks * 32 + (lane >> 4) * 8;
  half8 v;
#pragma unroll
  for (int j = 0; j < 8; ++j) v[j] = (_Float16)W[(size_t)(kb + j) * HID + n];
  *(half8*)(Bp + (((size_t)(tnBase + tn) * KS + ks) * 64 + lane) * 8) = v;
}

// ---------------- fp16 MFMA GEMM: C[M x 256] = A[M x K] @ [Bl | Br] ----------------
__global__ __launch_bounds__(512) void gemm_f16(
    const float* __restrict__ A32, const _Float16* __restrict__ A16,
    int M, int K,
    const _Float16* __restrict__ Bp,
    _Float16* __restrict__ C) {
  __shared__ _Float16 As[128][40];

  const int KS = K >> 5;
  const int tid = threadIdx.x;
  const int lane = tid & 63;
  const int wid = tid >> 6;
  const int quad = lane >> 4;
  const int lm = lane & 15;
  const int row0 = (wid & 1) * 64;
  const int ct0 = (wid >> 1) * 4;
  const int blockRow = blockIdx.x * 128;

  const int srow = tid >> 2;
  const int scol = (tid & 3) * 8;

  floatx4 acc[16];
#pragma unroll
  for (int i = 0; i < 16; ++i) {
    acc[i][0] = 0.f; acc[i][1] = 0.f; acc[i][2] = 0.f; acc[i][3] = 0.f;
  }

  for (int ks = 0; ks < KS; ++ks) {
    const int gr = blockRow + srow;
    half8 hv;
    if (A32) {
      float4 f0 = make_float4(0.f, 0.f, 0.f, 0.f), f1 = f0;
      if (gr < M) {
        const float* p = A32 + (size_t)gr * K + ks * 32 + scol;
        f0 = *(const float4*)p;
        f1 = *(const float4*)(p + 4);
      }
      hv[0] = (_Float16)f0.x; hv[1] = (_Float16)f0.y;
      hv[2] = (_Float16)f0.z; hv[3] = (_Float16)f0.w;
      hv[4] = (_Float16)f1.x; hv[5] = (_Float16)f1.y;
      hv[6] = (_Float16)f1.z; hv[7] = (_Float16)f1.w;
    } else {
      if (gr < M) {
        hv = *(const half8*)(A16 + (size_t)gr * K + ks * 32 + scol);
      } else {
#pragma unroll
        for (int j = 0; j < 8; ++j) hv[j] = (_Float16)0.f;
      }
    }
    __syncthreads();
    *(half8*)&As[srow][scol] = hv;
    __syncthreads();

    half8 af[4], bf[4];
#pragma unroll
    for (int rt = 0; rt < 4; ++rt)
      af[rt] = *(const half8*)&As[row0 + rt * 16 + lm][quad * 8];
#pragma unroll
    for (int ct = 0; ct < 4; ++ct) {
      const int tn = ct0 + ct;
      bf[ct] = *(const half8*)(Bp + (((size_t)tn * KS + ks) * 64 + lane) * 8);
    }
#pragma unroll
    for (int rt = 0; rt < 4; ++rt)
#pragma unroll
      for (int ct = 0; ct < 4; ++ct)
        acc[rt * 4 + ct] =
            __builtin_amdgcn_mfma_f32_16x16x32_f16(af[rt], bf[ct], acc[rt * 4 + ct], 0, 0, 0);
  }

#pragma unroll
  for (int rt = 0; rt < 4; ++rt) {
#pragma unroll
    for (int r = 0; r < 4; ++r) {
      const int gm = blockRow + row0 + rt * 16 + quad * 4 + r;
      if (gm < M) {
#pragma unroll
        for (int ct = 0; ct < 4; ++ct) {
          const int col = (ct0 + ct) * 16 + lm;
          C[(size_t)gm * 256 + col] = (_Float16)acc[rt * 4 + ct][r];
        }
      }
    }
  }
}

// ---------------- helpers ----------------
__device__ inline float2 upk(unsigned u) {
  union { unsigned v; _Float16 h[2]; } c; c.v = u;
  return make_float2((float)c.h[0], (float)c.h[1]);
}
__device__ inline half2v as_h2(unsigned u) {
  union { unsigned v; half2v h; } c; c.v = u;
  return c.h;
}
__device__ inline unsigned as_u32(half2v h) {
  union { half2v h; unsigned v; } c; c.h = h;
  return c.v;
}
__device__ inline unsigned pkadd(unsigned a, unsigned b) {
  return as_u32(as_h2(a) + as_h2(b));   // v_pk_add_f16
}
__device__ inline void pkacc4(uint4& A, const uint4& v) {
  A.x = pkadd(A.x, v.x); A.y = pkadd(A.y, v.y);
  A.z = pkadd(A.z, v.z); A.w = pkadd(A.w, v.w);
}

// ---------------- core gather: 1 node/wave, 16 col-lanes x 4 edge slots ----------------
// Each lane loads dwordx4 (16B) -> wave instruction gathers 4 full 256B rows (1KB).
// Packed-fp16 accumulation (4 v_pk_add per 16B). Returns slot-reduced sum in A
// (all lanes hold the total for their 16B column group).
__device__ inline uint4 gather_rows(const unsigned* __restrict__ yzu,
                                    const int* __restrict__ sorted_src,
                                    int start, int end, int cl, int slot) {
  uint4 A0 = make_uint4(0u, 0u, 0u, 0u);
  uint4 A1 = A0;
  int k = start + slot;
  for (; k + 12 < end; k += 16) {
    int s0 = sorted_src[k];
    int s1 = sorted_src[k + 4];
    int s2 = sorted_src[k + 8];
    int s3 = sorted_src[k + 12];
    uint4 v0 = *(const uint4*)(yzu + (size_t)s0 * 128 + cl * 4);
    uint4 v1 = *(const uint4*)(yzu + (size_t)s1 * 128 + cl * 4);
    uint4 v2 = *(const uint4*)(yzu + (size_t)s2 * 128 + cl * 4);
    uint4 v3 = *(const uint4*)(yzu + (size_t)s3 * 128 + cl * 4);
    pkacc4(A0, v0);
    pkacc4(A1, v1);
    pkacc4(A0, v2);
    pkacc4(A1, v3);
  }
  for (; k < end; k += 4) {
    int s = sorted_src[k];
    uint4 v = *(const uint4*)(yzu + (size_t)s * 128 + cl * 4);
    pkacc4(A0, v);
  }
  pkacc4(A0, A1);
  // reduce across the 4 edge slots (lanes xor 16, 32)
#pragma unroll
  for (int off = 16; off < 64; off <<= 1) {
    uint4 o;
    o.x = (unsigned)__shfl_xor((int)A0.x, off, 64);
    o.y = (unsigned)__shfl_xor((int)A0.y, off, 64);
    o.z = (unsigned)__shfl_xor((int)A0.z, off, 64);
    o.w = (unsigned)__shfl_xor((int)A0.w, off, 64);
    pkacc4(A0, o);
  }
  return A0;
}

// ---------------- layer-1 aggregate + combine + ReLU ----------------
// yz as u32: row stride 128 (=256 fp16); y half = cols 0..63, z half = 64..127.
__global__ __launch_bounds__(256) void agg_relu16(
    const unsigned* __restrict__ yzu, const int* __restrict__ sorted_src,
    const int* __restrict__ rs, const float* __restrict__ bias,
    unsigned* __restrict__ h1u, int N) {
  const int w = threadIdx.x >> 6;
  const int lane = threadIdx.x & 63;
  const int cl = lane & 15;
  const int slot = lane >> 4;
  const int node = blockIdx.x * 4 + w;
  if (node >= N) return;
  const int start = rs[node];
  const int end = rs[node + 1];
  uint4 A = gather_rows(yzu, sorted_src, start, end, cl, slot);
  if (slot == 0) {
    const int deg = end - start;
    const float inv = 1.f / (float)max(deg, 1);
    uint4 z4 = *(const uint4*)(yzu + (size_t)node * 128 + 64 + cl * 4);
    const unsigned av[4] = {A.x, A.y, A.z, A.w};
    const unsigned zv[4] = {z4.x, z4.y, z4.z, z4.w};
    uint4 o;
    unsigned ov[4];
#pragma unroll
    for (int q = 0; q < 4; ++q) {
      const int cp = cl * 4 + q;     // u32 column index
      float2 a = upk(av[q]);
      float2 z = upk(zv[q]);
      float vx = fmaxf(a.x * inv + bias[2 * cp] + z.x, 0.f);
      float vy = fmaxf(a.y * inv + bias[2 * cp + 1] + z.y, 0.f);
      union { unsigned v; _Float16 h[2]; } c;
      c.h[0] = (_Float16)vx; c.h[1] = (_Float16)vy;
      ov[q] = c.v;
    }
    o.x = ov[0]; o.y = ov[1]; o.z = ov[2]; o.w = ov[3];
    *(uint4*)(h1u + (size_t)node * 64 + cl * 4) = o;
  }
}

// ---------------- layer-2 aggregate + combine + fused scorer projection ----------------
__global__ __launch_bounds__(256) void agg_score16(
    const unsigned* __restrict__ yzu, const int* __restrict__ sorted_src,
    const int* __restrict__ rs, const float* __restrict__ bias,
    const float* __restrict__ Wlin,
    float* __restrict__ sa, float* __restrict__ sb, int N) {
  const int w = threadIdx.x >> 6;
  const int lane = threadIdx.x & 63;
  const int cl = lane & 15;
  const int slot = lane >> 4;
  const int node = blockIdx.x * 4 + w;
  if (node >= N) return;
  const int start = rs[node];
  const int end = rs[node + 1];
  uint4 A = gather_rows(yzu, sorted_src, start, end, cl, slot);
  const int deg = end - start;
  const float inv = 1.f / (float)max(deg, 1);
  uint4 z4 = *(const uint4*)(yzu + (size_t)node * 128 + 64 + cl * 4);
  const unsigned av[4] = {A.x, A.y, A.z, A.w};
  const unsigned zv[4] = {z4.x, z4.y, z4.z, z4.w};
  float pa = 0.f, pb = 0.f;
#pragma unroll
  for (int q = 0; q < 4; ++q) {
    const int cp = cl * 4 + q;
    float2 a = upk(av[q]);
    float2 z = upk(zv[q]);
    float hx = a.x * inv + bias[2 * cp] + z.x;
    float hy = a.y * inv + bias[2 * cp + 1] + z.y;
    pa += hx * Wlin[2 * cp] + hy * Wlin[2 * cp + 1];
    pb += hx * Wlin[128 + 2 * cp] + hy * Wlin[129 + 2 * cp];
  }
  // reduce over the 16 col-lanes (slots hold identical totals; lane 0 stores)
#pragma unroll
  for (int off = 1; off < 16; off <<= 1) {
    pa += __shfl_xor(pa, off, 64);
    pb += __shfl_xor(pb, off, 64);
  }
  if (lane == 0) {
    sa[node] = pa;
    sb[node] = pb;
  }
}

// ---------------- edge scoring: out[e] = s_a[i] + s_b[j] + b ----------------
__global__ void score_kernel(const int* __restrict__ idx, int E,
                             const float* __restrict__ sa, const float* __restrict__ sb,
                             const float* __restrict__ blin, float* __restrict__ out) {
  int e = blockIdx.x * 256 + threadIdx.x;
  if (e < E) out[e] = sa[idx[e]] + sb[idx[E + e]] + blin[0];
}

extern "C" void kernel_launch(void* const* d_in, const int* in_sizes, int n_in,
                              void* d_out, int out_size, void* d_ws, size_t ws_size,
                              hipStream_t stream) {
  (void)n_in; (void)out_size; (void)ws_size;
  const float* x    = (const float*)d_in[0];
  const int*   ei   = (const int*)d_in[1];
  const int*   pos  = (const int*)d_in[2];
  const int*   neg  = (const int*)d_in[3];
  const float* Wl1  = (const float*)d_in[4];
  const float* bl1  = (const float*)d_in[5];
  const float* Wr1  = (const float*)d_in[6];
  const float* Wl2  = (const float*)d_in[7];
  const float* bl2  = (const float*)d_in[8];
  const float* Wr2  = (const float*)d_in[9];
  const float* Wlin = (const float*)d_in[10];
  const float* blin = (const float*)d_in[11];

  const int N  = in_sizes[0] / IN_DIM;  // 100000
  const int E  = in_sizes[1] / 2;       // 3200000
  const int Ep = in_sizes[2] / 2;       // 500000
  const int En = in_sizes[3] / 2;       // 500000
  const int* e_src = ei;
  const int* e_dst = ei + E;

  char* ws = (char*)d_ws;
  size_t off = 0;
  auto carve = [&](size_t bytes) -> char* {
    char* p = ws + off;
    off += (bytes + 255) & ~(size_t)255;
    return p;
  };
  const int nB = (N + NPB - 1) / NPB;   // 391 buckets
  const int KS1 = IN_DIM / 32;          // 12
  const int KS2 = HID / 32;             // 4

  int*      rs     = (int*)carve((size_t)(N + 256) * 4);
  int*      bCnt   = (int*)carve(512 * 4);
  int*      bBase  = (int*)carve(512 * 4);
  int*      bCur   = (int*)carve(512 * 4);
  unsigned* bData  = (unsigned*)carve((size_t)E * 4);
  int*      sorted = (int*)carve((size_t)E * 4);
  float*    sa     = (float*)carve((size_t)N * 4);
  float*    sb     = (float*)carve((size_t)N * 4);
  _Float16* Bp1    = (_Float16*)carve((size_t)16 * KS1 * 64 * 8 * 2);
  _Float16* Bp2    = (_Float16*)carve((size_t)16 * KS2 * 64 * 8 * 2);
  _Float16* yz     = (_Float16*)carve((size_t)N * 256 * 2);
  _Float16* h1     = (_Float16*)carve((size_t)N * 128 * 2);

  const int gemmBlocks = (N + 127) / 128;
  const int partBlocks = (E + 8191) / 8192;  // 391

  // CSR build (no per-node global atomics)
  hipLaunchKernelGGL(zero_i32, dim3(2), dim3(256), 0, stream, bCnt, 512);
  hipLaunchKernelGGL(bucket_count, dim3(partBlocks), dim3(256), 0, stream,
                     e_dst, E, nB, bCnt);
  hipLaunchKernelGGL(scan_buckets, dim3(1), dim3(512), 0, stream,
                     bCnt, nB, E, N, bBase, bCur, rs);
  hipLaunchKernelGGL(partition_kernel, dim3(partBlocks), dim3(256), 0, stream,
                     e_src, e_dst, E, nB, bCur, bData);
  hipLaunchKernelGGL(node_sort2, dim3(nB), dim3(256), 0, stream,
                     bData, bBase, N, sorted, rs);

  // weight packing (tiny)
  hipLaunchKernelGGL(pack_w, dim3(8, KS1), dim3(64), 0, stream, Wl1, Bp1, 0);
  hipLaunchKernelGGL(pack_w, dim3(8, KS1), dim3(64), 0, stream, Wr1, Bp1, 8);
  hipLaunchKernelGGL(pack_w, dim3(8, KS2), dim3(64), 0, stream, Wl2, Bp2, 0);
  hipLaunchKernelGGL(pack_w, dim3(8, KS2), dim3(64), 0, stream, Wr2, Bp2, 8);

  // layer 1
  hipLaunchKernelGGL(gemm_f16, dim3(gemmBlocks), dim3(512), 0, stream,
                     x, (const _Float16*)nullptr, N, IN_DIM, Bp1, yz);
  hipLaunchKernelGGL(agg_relu16, dim3((N + 3) / 4), dim3(256), 0, stream,
                     (const unsigned*)yz, sorted, rs, bl1, (unsigned*)h1, N);
  // layer 2
  hipLaunchKernelGGL(gemm_f16, dim3(gemmBlocks), dim3(512), 0, stream,
                     (const float*)nullptr, h1, N, HID, Bp2, yz);
  hipLaunchKernelGGL(agg_score16, dim3((N + 3) / 4), dim3(256), 0, stream,
                     (const unsigned*)yz, sorted, rs, bl2, Wlin, sa, sb, N);

  // scoring
  float* out = (float*)d_out;
  hipLaunchKernelGGL(score_kernel, dim3((Ep + 255) / 256), dim3(256), 0, stream,
                     pos, Ep, sa, sb, blin, out);
  hipLaunchKernelGGL(score_kernel, dim3((En + 255) / 256), dim3(256), 0, stream,
                     neg, En, sa, sb, blin, out + Ep);
}

// Round 8
// 624.207 us; speedup vs baseline: 1.9564x; 1.0214x over previous
//
#include <hip/hip_runtime.h>

#define IN_DIM 384
#define HID    128
#define NPB    256            // nodes per bucket (dstLocal fits in 8 bits)
#define BCAP   16384          // fixed bucket capacity (max fill ~8.7k, 1.9x margin)

#define AS1 __attribute__((address_space(1)))
#define AS3 __attribute__((address_space(3)))

typedef _Float16 half8 __attribute__((ext_vector_type(8)));
typedef _Float16 half2t __attribute__((ext_vector_type(2)));
typedef __fp16 fp16x2 __attribute__((ext_vector_type(2)));
typedef float floatx4 __attribute__((ext_vector_type(4)));

// ---------------- utility ----------------
__global__ void zero_i32(int* __restrict__ p, int n) {
  int i = blockIdx.x * 256 + threadIdx.x;
  if (i < n) p[i] = 0;
}

// ---------------- phase 1: partition edges into fixed-capacity coarse buckets -------
// 8192 edges/block; packed value = (dstLocal << 17) | src  (src < 2^17, dstLocal < 256)
// Bucket b owns bData[b*BCAP ...]; bCur[b] ends as the bucket fill count.
__global__ __launch_bounds__(256) void partition_kernel(
    const int* __restrict__ src, const int* __restrict__ dst, int E, int nB,
    int* __restrict__ bCur, unsigned* __restrict__ bucketData) {
  __shared__ int hist[391];
  __shared__ int gbase[391];
  const int t = threadIdx.x;
  const int b0 = blockIdx.x * 8192;

  for (int i = t; i < nB; i += 256) hist[i] = 0;
  __syncthreads();
#pragma unroll
  for (int i = 0; i < 32; ++i) {
    int e = b0 + i * 256 + t;
    if (e < E) atomicAdd(&hist[dst[e] >> 8], 1);
  }
  __syncthreads();
  for (int i = t; i < nB; i += 256) {
    int h = hist[i];
    gbase[i] = h ? (i * BCAP + atomicAdd(&bCur[i], h)) : 0;
    hist[i] = 0;
  }
  __syncthreads();
#pragma unroll
  for (int i = 0; i < 32; ++i) {
    int e = b0 + i * 256 + t;
    if (e < E) {
      int d = dst[e];
      int b = d >> 8;
      int r = atomicAdd(&hist[b], 1);
      bucketData[gbase[b] + r] = ((unsigned)(d & 255) << 17) | (unsigned)src[e];
    }
  }
}

// ---------------- phase 2: per-bucket node histogram + scan + scatter ----------------
// Emits per-node [rs, re) ranges into the padded sorted_src layout; no global atomics.
__global__ __launch_bounds__(256) void node_sort2(
    const unsigned* __restrict__ bucketData, const int* __restrict__ bCur,
    int N, int* __restrict__ sorted_src, int* __restrict__ rs, int* __restrict__ re) {
  __shared__ int hist[NPB];
  __shared__ int s[NPB];
  __shared__ int cur[NPB];
  const int b = blockIdx.x;
  const int t = threadIdx.x;
  const int start = b * BCAP;
  const int end = start + bCur[b];
  hist[t] = 0;
  __syncthreads();
  for (int e = start + t; e < end; e += 256) atomicAdd(&hist[bucketData[e] >> 17], 1);
  __syncthreads();
  int v = hist[t];
  s[t] = v;
  __syncthreads();
  for (int off = 1; off < 256; off <<= 1) {
    int y = (t >= off) ? s[t - off] : 0;
    __syncthreads();
    s[t] += y;
    __syncthreads();
  }
  int excl = s[t] - v;
  const int node = b * NPB + t;
  if (node < N) {
    rs[node] = start + excl;
    re[node] = start + excl + v;
  }
  cur[t] = start + excl;
  __syncthreads();
  for (int e = start + t; e < end; e += 256) {
    unsigned d = bucketData[e];
    int p = atomicAdd(&cur[d >> 17], 1);
    sorted_src[p] = (int)(d & 0x1FFFF);
  }
}

// ---------------- weight pack: W[K][128] fp32 -> per-lane MFMA B-fragment order ------
__global__ void pack_w(const float* __restrict__ W, _Float16* __restrict__ Bp,
                       int tnBase) {
  const int tn = blockIdx.x;
  const int ks = blockIdx.y;
  const int KS = gridDim.y;
  const int lane = threadIdx.x;
  const int n = tn * 16 + (lane & 15);
  const int kb = ks * 32 + (lane >> 4) * 8;
  half8 v;
#pragma unroll
  for (int j = 0; j < 8; ++j) v[j] = (_Float16)W[(size_t)(kb + j) * HID + n];
  *(half8*)(Bp + (((size_t)(tnBase + tn) * KS + ks) * 64 + lane) * 8) = v;
}

// ---------------- cvt helper: pack two fp32 -> fp16x2 (RTZ), as half2t --------------
__device__ inline half2t cvt_pk(float a, float b) {
  fp16x2 r = __builtin_amdgcn_cvt_pkrtz(a, b);
  union { fp16x2 f; half2t h; } c;
  c.f = r;
  return c.h;
}

// ---------------- GEMM (fp32 A): C[M x 256] = A[M x K] @ [Bl | Br], K = IN_DIM -------
// Block 128x256, 512 thr / 8 waves, wave = 64x64 via 4x4 of 16x16x32 MFMA.
// A staged raw fp32 via global_load_lds (16B/lane), XOR-swizzled LDS (colgroup ^ row&7)
// -> 2-way bank alias (free). fp32->fp16 cvt_pkrtz at fragment read.
__global__ __launch_bounds__(512) void gemm_f32a(
    const float* __restrict__ A, int M,
    const _Float16* __restrict__ Bp, _Float16* __restrict__ C) {
  __shared__ float As[128 * 32];   // (row*8 + cg_phys)*4 floats, cg_phys = cg ^ (row&7)

  const int K = IN_DIM, KS = IN_DIM / 32;
  const int tid = threadIdx.x;
  const int lane = tid & 63;
  const int wid = tid >> 6;
  const int quad = lane >> 4;
  const int lm = lane & 15;
  const int row0 = (wid & 1) * 64;
  const int ct0 = (wid >> 1) * 4;
  const int blockRow = blockIdx.x * 128;

  // staging lane map: row_local = lane>>3 (8 rows/issue), logical cg = (lane&7)^(row&7)
  const int srow = lane >> 3;
  const int scol = ((lane & 7) ^ (srow & 7)) * 4;
  const int grow0 = min(blockRow + wid * 16 + srow, M - 1);
  const int grow1 = min(blockRow + wid * 16 + 8 + srow, M - 1);

  floatx4 acc[16];
#pragma unroll
  for (int i = 0; i < 16; ++i) {
    acc[i][0] = 0.f; acc[i][1] = 0.f; acc[i][2] = 0.f; acc[i][3] = 0.f;
  }

  for (int ks = 0; ks < KS; ++ks) {
    const int k0 = ks * 32;
    __syncthreads();   // prior iteration's LDS reads complete
    __builtin_amdgcn_global_load_lds(
        (const AS1 void*)(A + (size_t)grow0 * K + k0 + scol),
        (AS3 void*)(As + (wid * 16) * 32), 16, 0, 0);
    __builtin_amdgcn_global_load_lds(
        (const AS1 void*)(A + (size_t)grow1 * K + k0 + scol),
        (AS3 void*)(As + (wid * 16 + 8) * 32), 16, 0, 0);

    // B fragments (L2-hot) overlap the DMA
    half8 bf[4];
#pragma unroll
    for (int ct = 0; ct < 4; ++ct)
      bf[ct] = *(const half8*)(Bp + (((size_t)(ct0 + ct) * KS + ks) * 64 + lane) * 8);

    __syncthreads();   // DMA visible

    half8 af[4];
#pragma unroll
    for (int rt = 0; rt < 4; ++rt) {
      const int row = row0 + rt * 16 + lm;
      const int sw = row & 7;
      const floatx4 fA = *(const floatx4*)&As[(row * 8 + ((quad * 2) ^ sw)) * 4];
      const floatx4 fB = *(const floatx4*)&As[(row * 8 + ((quad * 2 + 1) ^ sw)) * 4];
      half2t h01 = cvt_pk(fA[0], fA[1]);
      half2t h23 = cvt_pk(fA[2], fA[3]);
      half2t h45 = cvt_pk(fB[0], fB[1]);
      half2t h67 = cvt_pk(fB[2], fB[3]);
      half8 a;
      a[0] = h01[0]; a[1] = h01[1]; a[2] = h23[0]; a[3] = h23[1];
      a[4] = h45[0]; a[5] = h45[1]; a[6] = h67[0]; a[7] = h67[1];
      af[rt] = a;
    }
#pragma unroll
    for (int rt = 0; rt < 4; ++rt)
#pragma unroll
      for (int ct = 0; ct < 4; ++ct)
        acc[rt * 4 + ct] =
            __builtin_amdgcn_mfma_f32_16x16x32_f16(af[rt], bf[ct], acc[rt * 4 + ct], 0, 0, 0);
  }

#pragma unroll
  for (int rt = 0; rt < 4; ++rt) {
#pragma unroll
    for (int r = 0; r < 4; ++r) {
      const int gm = blockRow + row0 + rt * 16 + quad * 4 + r;
      if (gm < M) {
#pragma unroll
        for (int ct = 0; ct < 4; ++ct)
          C[(size_t)gm * 256 + (ct0 + ct) * 16 + lm] = (_Float16)acc[rt * 4 + ct][r];
      }
    }
  }
}

// ---------------- GEMM (fp16 A): C[M x 256] = A[M x 128] @ [Bl | Br] ----------------
// A staged fp16 via global_load_lds; swizzle colgroup ^ ((row>>1)&3) -> 2-way alias.
__global__ __launch_bounds__(512) void gemm_f16a(
    const _Float16* __restrict__ A, int M,
    const _Float16* __restrict__ Bp, _Float16* __restrict__ C) {
  __shared__ _Float16 As[128 * 32];  // (row*4 + cg_phys)*8 halfs

  const int K = HID, KS = HID / 32;
  const int tid = threadIdx.x;
  const int lane = tid & 63;
  const int wid = tid >> 6;
  const int quad = lane >> 4;
  const int lm = lane & 15;
  const int row0 = (wid & 1) * 64;
  const int ct0 = (wid >> 1) * 4;
  const int blockRow = blockIdx.x * 128;

  // staging: row_local = lane>>2 (16 rows/issue), logical cg = (lane&3)^((lane>>3)&3)
  const int srow = lane >> 2;
  const int scol = ((lane & 3) ^ ((lane >> 3) & 3)) * 8;
  const int grow = min(blockRow + wid * 16 + srow, M - 1);

  floatx4 acc[16];
#pragma unroll
  for (int i = 0; i < 16; ++i) {
    acc[i][0] = 0.f; acc[i][1] = 0.f; acc[i][2] = 0.f; acc[i][3] = 0.f;
  }

  for (int ks = 0; ks < KS; ++ks) {
    const int k0 = ks * 32;
    __syncthreads();
    __builtin_amdgcn_global_load_lds(
        (const AS1 void*)(A + (size_t)grow * K + k0 + scol),
        (AS3 void*)(As + (wid * 16) * 32), 16, 0, 0);

    half8 bf[4];
#pragma unroll
    for (int ct = 0; ct < 4; ++ct)
      bf[ct] = *(const half8*)(Bp + (((size_t)(ct0 + ct) * KS + ks) * 64 + lane) * 8);

    __syncthreads();

    half8 af[4];
#pragma unroll
    for (int rt = 0; rt < 4; ++rt) {
      const int row = row0 + rt * 16 + lm;
      const int cg = quad ^ ((row >> 1) & 3);
      af[rt] = *(const half8*)&As[(row * 4 + cg) * 8];
    }
#pragma unroll
    for (int rt = 0; rt < 4; ++rt)
#pragma unroll
      for (int ct = 0; ct < 4; ++ct)
        acc[rt * 4 + ct] =
            __builtin_amdgcn_mfma_f32_16x16x32_f16(af[rt], bf[ct], acc[rt * 4 + ct], 0, 0, 0);
  }

#pragma unroll
  for (int rt = 0; rt < 4; ++rt) {
#pragma unroll
    for (int r = 0; r < 4; ++r) {
      const int gm = blockRow + row0 + rt * 16 + quad * 4 + r;
      if (gm < M) {
#pragma unroll
        for (int ct = 0; ct < 4; ++ct)
          C[(size_t)gm * 256 + (ct0 + ct) * 16 + lm] = (_Float16)acc[rt * 4 + ct][r];
      }
    }
  }
}

// ---------------- helpers ----------------
__device__ inline float2 upk(unsigned u) {
  union { unsigned v; _Float16 h[2]; } c; c.v = u;
  return make_float2((float)c.h[0], (float)c.h[1]);
}
__device__ inline half2t as_h2(unsigned u) {
  union { unsigned v; half2t h; } c; c.v = u;
  return c.h;
}
__device__ inline unsigned as_u32(half2t h) {
  union { half2t h; unsigned v; } c; c.h = h;
  return c.v;
}
__device__ inline unsigned pkadd(unsigned a, unsigned b) {
  return as_u32(as_h2(a) + as_h2(b));   // v_pk_add_f16
}
__device__ inline void pkacc4(uint4& A, const uint4& v) {
  A.x = pkadd(A.x, v.x); A.y = pkadd(A.y, v.y);
  A.z = pkadd(A.z, v.z); A.w = pkadd(A.w, v.w);
}

// ---------------- core gather: 1 node/wave, 16 col-lanes x 4 edge slots --------------
__device__ inline uint4 gather_rows(const unsigned* __restrict__ yzu,
                                    const int* __restrict__ sorted_src,
                                    int start, int end, int cl, int slot) {
  uint4 A0 = make_uint4(0u, 0u, 0u, 0u);
  uint4 A1 = A0;
  int k = start + slot;
  for (; k + 12 < end; k += 16) {
    int s0 = sorted_src[k];
    int s1 = sorted_src[k + 4];
    int s2 = sorted_src[k + 8];
    int s3 = sorted_src[k + 12];
    uint4 v0 = *(const uint4*)(yzu + (size_t)s0 * 128 + cl * 4);
    uint4 v1 = *(const uint4*)(yzu + (size_t)s1 * 128 + cl * 4);
    uint4 v2 = *(const uint4*)(yzu + (size_t)s2 * 128 + cl * 4);
    uint4 v3 = *(const uint4*)(yzu + (size_t)s3 * 128 + cl * 4);
    pkacc4(A0, v0);
    pkacc4(A1, v1);
    pkacc4(A0, v2);
    pkacc4(A1, v3);
  }
  if (k + 4 < end) {   // 2-deep tail
    int s0 = sorted_src[k];
    int s1 = sorted_src[k + 4];
    uint4 v0 = *(const uint4*)(yzu + (size_t)s0 * 128 + cl * 4);
    uint4 v1 = *(const uint4*)(yzu + (size_t)s1 * 128 + cl * 4);
    pkacc4(A0, v0);
    pkacc4(A1, v1);
    k += 8;
  }
  if (k < end) {
    int s = sorted_src[k];
    uint4 v = *(const uint4*)(yzu + (size_t)s * 128 + cl * 4);
    pkacc4(A0, v);
  }
  pkacc4(A0, A1);
#pragma unroll
  for (int off = 16; off < 64; off <<= 1) {
    uint4 o;
    o.x = (unsigned)__shfl_xor((int)A0.x, off, 64);
    o.y = (unsigned)__shfl_xor((int)A0.y, off, 64);
    o.z = (unsigned)__shfl_xor((int)A0.z, off, 64);
    o.w = (unsigned)__shfl_xor((int)A0.w, off, 64);
    pkacc4(A0, o);
  }
  return A0;
}

// ---------------- layer-1 aggregate + combine + ReLU ----------------
__global__ __launch_bounds__(256) void agg_relu16(
    const unsigned* __restrict__ yzu, const int* __restrict__ sorted_src,
    const int* __restrict__ rs, const int* __restrict__ re,
    const float* __restrict__ bias, unsigned* __restrict__ h1u, int N) {
  const int w = threadIdx.x >> 6;
  const int lane = threadIdx.x & 63;
  const int cl = lane & 15;
  const int slot = lane >> 4;
  const int node = blockIdx.x * 4 + w;
  if (node >= N) return;
  const int start = rs[node];
  const int end = re[node];
  uint4 A = gather_rows(yzu, sorted_src, start, end, cl, slot);
  if (slot == 0) {
    const int deg = end - start;
    const float inv = 1.f / (float)max(deg, 1);
    uint4 z4 = *(const uint4*)(yzu + (size_t)node * 128 + 64 + cl * 4);
    const unsigned av[4] = {A.x, A.y, A.z, A.w};
    const unsigned zv[4] = {z4.x, z4.y, z4.z, z4.w};
    uint4 o;
    unsigned ov[4];
#pragma unroll
    for (int q = 0; q < 4; ++q) {
      const int cp = cl * 4 + q;
      float2 a = upk(av[q]);
      float2 z = upk(zv[q]);
      float vx = fmaxf(a.x * inv + bias[2 * cp] + z.x, 0.f);
      float vy = fmaxf(a.y * inv + bias[2 * cp + 1] + z.y, 0.f);
      union { unsigned v; _Float16 h[2]; } c;
      c.h[0] = (_Float16)vx; c.h[1] = (_Float16)vy;
      ov[q] = c.v;
    }
    o.x = ov[0]; o.y = ov[1]; o.z = ov[2]; o.w = ov[3];
    *(uint4*)(h1u + (size_t)node * 64 + cl * 4) = o;
  }
}

// ---------------- layer-2 aggregate + combine + fused scorer projection --------------
__global__ __launch_bounds__(256) void agg_score16(
    const unsigned* __restrict__ yzu, const int* __restrict__ sorted_src,
    const int* __restrict__ rs, const int* __restrict__ re,
    const float* __restrict__ bias, const float* __restrict__ Wlin,
    float* __restrict__ sa, float* __restrict__ sb, int N) {
  const int w = threadIdx.x >> 6;
  const int lane = threadIdx.x & 63;
  const int cl = lane & 15;
  const int slot = lane >> 4;
  const int node = blockIdx.x * 4 + w;
  if (node >= N) return;
  const int start = rs[node];
  const int end = re[node];
  uint4 A = gather_rows(yzu, sorted_src, start, end, cl, slot);
  const int deg = end - start;
  const float inv = 1.f / (float)max(deg, 1);
  uint4 z4 = *(const uint4*)(yzu + (size_t)node * 128 + 64 + cl * 4);
  const unsigned av[4] = {A.x, A.y, A.z, A.w};
  const unsigned zv[4] = {z4.x, z4.y, z4.z, z4.w};
  float pa = 0.f, pb = 0.f;
#pragma unroll
  for (int q = 0; q < 4; ++q) {
    const int cp = cl * 4 + q;
    float2 a = upk(av[q]);
    float2 z = upk(zv[q]);
    float hx = a.x * inv + bias[2 * cp] + z.x;
    float hy = a.y * inv + bias[2 * cp + 1] + z.y;
    pa += hx * Wlin[2 * cp] + hy * Wlin[2 * cp + 1];
    pb += hx * Wlin[128 + 2 * cp] + hy * Wlin[129 + 2 * cp];
  }
#pragma unroll
  for (int off = 1; off < 16; off <<= 1) {
    pa += __shfl_xor(pa, off, 64);
    pb += __shfl_xor(pb, off, 64);
  }
  if (lane == 0) {
    sa[node] = pa;
    sb[node] = pb;
  }
}

// ---------------- edge scoring: out[e] = s_a[i] + s_b[j] + b ----------------
__global__ void score_kernel(const int* __restrict__ idx, int E,
                             const float* __restrict__ sa, const float* __restrict__ sb,
                             const float* __restrict__ blin, float* __restrict__ out) {
  int e = blockIdx.x * 256 + threadIdx.x;
  if (e < E) out[e] = sa[idx[e]] + sb[idx[E + e]] + blin[0];
}

extern "C" void kernel_launch(void* const* d_in, const int* in_sizes, int n_in,
                              void* d_out, int out_size, void* d_ws, size_t ws_size,
                              hipStream_t stream) {
  (void)n_in; (void)out_size; (void)ws_size;
  const float* x    = (const float*)d_in[0];
  const int*   ei   = (const int*)d_in[1];
  const int*   pos  = (const int*)d_in[2];
  const int*   neg  = (const int*)d_in[3];
  const float* Wl1  = (const float*)d_in[4];
  const float* bl1  = (const float*)d_in[5];
  const float* Wr1  = (const float*)d_in[6];
  const float* Wl2  = (const float*)d_in[7];
  const float* bl2  = (const float*)d_in[8];
  const float* Wr2  = (const float*)d_in[9];
  const float* Wlin = (const float*)d_in[10];
  const float* blin = (const float*)d_in[11];

  const int N  = in_sizes[0] / IN_DIM;  // 100000
  const int E  = in_sizes[1] / 2;       // 3200000
  const int Ep = in_sizes[2] / 2;       // 500000
  const int En = in_sizes[3] / 2;       // 500000
  const int* e_src = ei;
  const int* e_dst = ei + E;

  char* ws = (char*)d_ws;
  size_t off = 0;
  auto carve = [&](size_t bytes) -> char* {
    char* p = ws + off;
    off += (bytes + 255) & ~(size_t)255;
    return p;
  };
  const int nB = (N + NPB - 1) / NPB;   // 391 buckets
  const int KS1 = IN_DIM / 32;          // 12
  const int KS2 = HID / 32;             // 4

  int*      rs     = (int*)carve((size_t)N * 4);
  int*      re     = (int*)carve((size_t)N * 4);
  int*      bCur   = (int*)carve(512 * 4);
  unsigned* bData  = (unsigned*)carve((size_t)nB * BCAP * 4);
  int*      sorted = (int*)carve((size_t)nB * BCAP * 4);
  float*    sa     = (float*)carve((size_t)N * 4);
  float*    sb     = (float*)carve((size_t)N * 4);
  _Float16* Bp1    = (_Float16*)carve((size_t)16 * KS1 * 64 * 8 * 2);
  _Float16* Bp2    = (_Float16*)carve((size_t)16 * KS2 * 64 * 8 * 2);
  _Float16* yz     = (_Float16*)carve((size_t)N * 256 * 2);
  _Float16* h1     = (_Float16*)carve((size_t)N * 128 * 2);

  const int gemmBlocks = (N + 127) / 128;
  const int partBlocks = (E + 8191) / 8192;  // 391

  // CSR build (fixed-capacity buckets; no count/scan kernels)
  hipLaunchKernelGGL(zero_i32, dim3(2), dim3(256), 0, stream, bCur, 512);
  hipLaunchKernelGGL(partition_kernel, dim3(partBlocks), dim3(256), 0, stream,
                     e_src, e_dst, E, nB, bCur, bData);
  hipLaunchKernelGGL(node_sort2, dim3(nB), dim3(256), 0, stream,
                     bData, bCur, N, sorted, rs, re);

  // weight packing (tiny)
  hipLaunchKernelGGL(pack_w, dim3(8, KS1), dim3(64), 0, stream, Wl1, Bp1, 0);
  hipLaunchKernelGGL(pack_w, dim3(8, KS1), dim3(64), 0, stream, Wr1, Bp1, 8);
  hipLaunchKernelGGL(pack_w, dim3(8, KS2), dim3(64), 0, stream, Wl2, Bp2, 0);
  hipLaunchKernelGGL(pack_w, dim3(8, KS2), dim3(64), 0, stream, Wr2, Bp2, 8);

  // layer 1
  hipLaunchKernelGGL(gemm_f32a, dim3(gemmBlocks), dim3(512), 0, stream,
                     x, N, Bp1, yz);
  hipLaunchKernelGGL(agg_relu16, dim3((N + 3) / 4), dim3(256), 0, stream,
                     (const unsigned*)yz, sorted, rs, re, bl1, (unsigned*)h1, N);
  // layer 2
  hipLaunchKernelGGL(gemm_f16a, dim3(gemmBlocks), dim3(512), 0, stream,
                     h1, N, Bp2, yz);
  hipLaunchKernelGGL(agg_score16, dim3((N + 3) / 4), dim3(256), 0, stream,
                     (const unsigned*)yz, sorted, rs, re, bl2, Wlin, sa, sb, N);

  // scoring
  float* out = (float*)d_out;
  hipLaunchKernelGGL(score_kernel, dim3((Ep + 255) / 256), dim3(256), 0, stream,
                     pos, Ep, sa, sb, blin, out);
  hipLaunchKernelGGL(score_kernel, dim3((En + 255) / 256), dim3(256), 0, stream,
                     neg, En, sa, sb, blin, out + Ep);
}

// Round 9
// 594.868 us; speedup vs baseline: 2.0529x; 1.0493x over previous
//
#include <hip/hip_runtime.h>

#define IN_DIM 384
#define HID    128
#define NPB    256            // nodes per bucket (dstLocal fits in 8 bits)
#define BCAP   16384          // fixed bucket capacity (max fill ~8.7k, 1.9x margin)
#define LCAP   10240          // LDS-resident bucket capacity (40KB)

#define AS1 __attribute__((address_space(1)))
#define AS3 __attribute__((address_space(3)))

typedef _Float16 half8 __attribute__((ext_vector_type(8)));
typedef _Float16 half2t __attribute__((ext_vector_type(2)));
typedef __fp16 fp16x2 __attribute__((ext_vector_type(2)));
typedef float floatx4 __attribute__((ext_vector_type(4)));

// ---------------- utility ----------------
__global__ void zero_i32(int* __restrict__ p, int n) {
  int i = blockIdx.x * 256 + threadIdx.x;
  if (i < n) p[i] = 0;
}

// ---------------- phase 1: partition edges into fixed-capacity coarse buckets -------
// 8192 edges/block, 512 threads (8 waves); packed value = (dstLocal << 17) | src
__global__ __launch_bounds__(512) void partition_kernel(
    const int* __restrict__ src, const int* __restrict__ dst, int E, int nB,
    int* __restrict__ bCur, unsigned* __restrict__ bucketData) {
  __shared__ int hist[391];
  __shared__ int gbase[391];
  const int t = threadIdx.x;
  const int b0 = blockIdx.x * 8192;

  for (int i = t; i < nB; i += 512) hist[i] = 0;
  __syncthreads();
#pragma unroll
  for (int i = 0; i < 16; ++i) {
    int e = b0 + i * 512 + t;
    if (e < E) atomicAdd(&hist[dst[e] >> 8], 1);
  }
  __syncthreads();
  for (int i = t; i < nB; i += 512) {
    int h = hist[i];
    gbase[i] = h ? (i * BCAP + atomicAdd(&bCur[i], h)) : 0;
    hist[i] = 0;
  }
  __syncthreads();
#pragma unroll
  for (int i = 0; i < 16; ++i) {
    int e = b0 + i * 512 + t;
    if (e < E) {
      int d = dst[e];
      int b = d >> 8;
      int r = atomicAdd(&hist[b], 1);
      bucketData[gbase[b] + r] = ((unsigned)(d & 255) << 17) | (unsigned)src[e];
    }
  }
}

// ---------------- phase 2: per-bucket node histogram + scan + scatter ----------------
// 1024 threads (16 waves). Bucket staged in dynamic LDS (single global read of bData);
// histogram fused into the staging pass. Emits per-node [rs, re) ranges.
__global__ __launch_bounds__(1024) void node_sort3(
    const unsigned* __restrict__ bucketData, const int* __restrict__ bCur,
    int N, int* __restrict__ sorted_src, int* __restrict__ rs, int* __restrict__ re) {
  extern __shared__ unsigned sdata[];          // LCAP entries
  __shared__ int hist[NPB];
  __shared__ int s[NPB];
  __shared__ int cur[NPB];
  const int b = blockIdx.x;
  const int t = threadIdx.x;
  const int start = b * BCAP;
  const int fill = bCur[b];
  if (t < NPB) hist[t] = 0;
  __syncthreads();
  // stage + histogram in one pass
  for (int i = t; i < fill; i += 1024) {
    unsigned d = bucketData[start + i];
    if (i < LCAP) sdata[i] = d;
    atomicAdd(&hist[d >> 17], 1);
  }
  __syncthreads();
  // scan over 256 node counters (t<256 active; all threads hit barriers)
  int v = 0;
  if (t < NPB) { v = hist[t]; s[t] = v; }
  __syncthreads();
  for (int off = 1; off < NPB; off <<= 1) {
    int y = (t < NPB && t >= off) ? s[t - off] : 0;
    __syncthreads();
    if (t < NPB) s[t] += y;
    __syncthreads();
  }
  if (t < NPB) {
    int excl = s[t] - v;
    const int node = b * NPB + t;
    if (node < N) {
      rs[node] = start + excl;
      re[node] = start + excl + v;
    }
    cur[t] = start + excl;
  }
  __syncthreads();
  // scatter from LDS (global fallback for statistically-impossible overflow)
  for (int i = t; i < fill; i += 1024) {
    unsigned d = (i < LCAP) ? sdata[i] : bucketData[start + i];
    int p = atomicAdd(&cur[d >> 17], 1);
    sorted_src[p] = (int)(d & 0x1FFFF);
  }
}

// ---------------- weight pack: W[K][128] fp32 -> per-lane MFMA B-fragment order ------
// grid (8, KS, 2): z=0 -> Wl (tn 0..7), z=1 -> Wr (tn 8..15)
__global__ void pack_w2(const float* __restrict__ Wl, const float* __restrict__ Wr,
                        _Float16* __restrict__ Bp) {
  const float* __restrict__ W = blockIdx.z ? Wr : Wl;
  const int tn = blockIdx.x;
  const int ks = blockIdx.y;
  const int KS = gridDim.y;
  const int lane = threadIdx.x;
  const int n = tn * 16 + (lane & 15);
  const int kb = ks * 32 + (lane >> 4) * 8;
  half8 v;
#pragma unroll
  for (int j = 0; j < 8; ++j) v[j] = (_Float16)W[(size_t)(kb + j) * HID + n];
  *(half8*)(Bp + (((size_t)(blockIdx.z * 8 + tn) * KS + ks) * 64 + lane) * 8) = v;
}

// ---------------- cvt helper: pack two fp32 -> fp16x2 (RTZ), as half2t --------------
__device__ inline half2t cvt_pk(float a, float b) {
  fp16x2 r = __builtin_amdgcn_cvt_pkrtz(a, b);
  union { fp16x2 f; half2t h; } c;
  c.f = r;
  return c.h;
}

// ---------------- GEMM (fp32 A): C[M x 256] = A[M x K] @ [Bl | Br], K = IN_DIM -------
__global__ __launch_bounds__(512) void gemm_f32a(
    const float* __restrict__ A, int M,
    const _Float16* __restrict__ Bp, _Float16* __restrict__ C) {
  __shared__ float As[128 * 32];   // (row*8 + cg_phys)*4 floats, cg_phys = cg ^ (row&7)

  const int K = IN_DIM, KS = IN_DIM / 32;
  const int tid = threadIdx.x;
  const int lane = tid & 63;
  const int wid = tid >> 6;
  const int quad = lane >> 4;
  const int lm = lane & 15;
  const int row0 = (wid & 1) * 64;
  const int ct0 = (wid >> 1) * 4;
  const int blockRow = blockIdx.x * 128;

  const int srow = lane >> 3;
  const int scol = ((lane & 7) ^ (srow & 7)) * 4;
  const int grow0 = min(blockRow + wid * 16 + srow, M - 1);
  const int grow1 = min(blockRow + wid * 16 + 8 + srow, M - 1);

  floatx4 acc[16];
#pragma unroll
  for (int i = 0; i < 16; ++i) {
    acc[i][0] = 0.f; acc[i][1] = 0.f; acc[i][2] = 0.f; acc[i][3] = 0.f;
  }

  for (int ks = 0; ks < KS; ++ks) {
    const int k0 = ks * 32;
    __syncthreads();
    __builtin_amdgcn_global_load_lds(
        (const AS1 void*)(A + (size_t)grow0 * K + k0 + scol),
        (AS3 void*)(As + (wid * 16) * 32), 16, 0, 0);
    __builtin_amdgcn_global_load_lds(
        (const AS1 void*)(A + (size_t)grow1 * K + k0 + scol),
        (AS3 void*)(As + (wid * 16 + 8) * 32), 16, 0, 0);

    half8 bf[4];
#pragma unroll
    for (int ct = 0; ct < 4; ++ct)
      bf[ct] = *(const half8*)(Bp + (((size_t)(ct0 + ct) * KS + ks) * 64 + lane) * 8);

    __syncthreads();

    half8 af[4];
#pragma unroll
    for (int rt = 0; rt < 4; ++rt) {
      const int row = row0 + rt * 16 + lm;
      const int sw = row & 7;
      const floatx4 fA = *(const floatx4*)&As[(row * 8 + ((quad * 2) ^ sw)) * 4];
      const floatx4 fB = *(const floatx4*)&As[(row * 8 + ((quad * 2 + 1) ^ sw)) * 4];
      half2t h01 = cvt_pk(fA[0], fA[1]);
      half2t h23 = cvt_pk(fA[2], fA[3]);
      half2t h45 = cvt_pk(fB[0], fB[1]);
      half2t h67 = cvt_pk(fB[2], fB[3]);
      half8 a;
      a[0] = h01[0]; a[1] = h01[1]; a[2] = h23[0]; a[3] = h23[1];
      a[4] = h45[0]; a[5] = h45[1]; a[6] = h67[0]; a[7] = h67[1];
      af[rt] = a;
    }
#pragma unroll
    for (int rt = 0; rt < 4; ++rt)
#pragma unroll
      for (int ct = 0; ct < 4; ++ct)
        acc[rt * 4 + ct] =
            __builtin_amdgcn_mfma_f32_16x16x32_f16(af[rt], bf[ct], acc[rt * 4 + ct], 0, 0, 0);
  }

#pragma unroll
  for (int rt = 0; rt < 4; ++rt) {
#pragma unroll
    for (int r = 0; r < 4; ++r) {
      const int gm = blockRow + row0 + rt * 16 + quad * 4 + r;
      if (gm < M) {
#pragma unroll
        for (int ct = 0; ct < 4; ++ct)
          C[(size_t)gm * 256 + (ct0 + ct) * 16 + lm] = (_Float16)acc[rt * 4 + ct][r];
      }
    }
  }
}

// ---------------- GEMM (fp16 A): C[M x 256] = A[M x 128] @ [Bl | Br] ----------------
__global__ __launch_bounds__(512) void gemm_f16a(
    const _Float16* __restrict__ A, int M,
    const _Float16* __restrict__ Bp, _Float16* __restrict__ C) {
  __shared__ _Float16 As[128 * 32];  // (row*4 + cg_phys)*8 halfs

  const int K = HID, KS = HID / 32;
  const int tid = threadIdx.x;
  const int lane = tid & 63;
  const int wid = tid >> 6;
  const int quad = lane >> 4;
  const int lm = lane & 15;
  const int row0 = (wid & 1) * 64;
  const int ct0 = (wid >> 1) * 4;
  const int blockRow = blockIdx.x * 128;

  const int srow = lane >> 2;
  const int scol = ((lane & 3) ^ ((lane >> 3) & 3)) * 8;
  const int grow = min(blockRow + wid * 16 + srow, M - 1);

  floatx4 acc[16];
#pragma unroll
  for (int i = 0; i < 16; ++i) {
    acc[i][0] = 0.f; acc[i][1] = 0.f; acc[i][2] = 0.f; acc[i][3] = 0.f;
  }

  for (int ks = 0; ks < KS; ++ks) {
    const int k0 = ks * 32;
    __syncthreads();
    __builtin_amdgcn_global_load_lds(
        (const AS1 void*)(A + (size_t)grow * K + k0 + scol),
        (AS3 void*)(As + (wid * 16) * 32), 16, 0, 0);

    half8 bf[4];
#pragma unroll
    for (int ct = 0; ct < 4; ++ct)
      bf[ct] = *(const half8*)(Bp + (((size_t)(ct0 + ct) * KS + ks) * 64 + lane) * 8);

    __syncthreads();

    half8 af[4];
#pragma unroll
    for (int rt = 0; rt < 4; ++rt) {
      const int row = row0 + rt * 16 + lm;
      const int cg = quad ^ ((row >> 1) & 3);
      af[rt] = *(const half8*)&As[(row * 4 + cg) * 8];
    }
#pragma unroll
    for (int rt = 0; rt < 4; ++rt)
#pragma unroll
      for (int ct = 0; ct < 4; ++ct)
        acc[rt * 4 + ct] =
            __builtin_amdgcn_mfma_f32_16x16x32_f16(af[rt], bf[ct], acc[rt * 4 + ct], 0, 0, 0);
  }

#pragma unroll
  for (int rt = 0; rt < 4; ++rt) {
#pragma unroll
    for (int r = 0; r < 4; ++r) {
      const int gm = blockRow + row0 + rt * 16 + quad * 4 + r;
      if (gm < M) {
#pragma unroll
        for (int ct = 0; ct < 4; ++ct)
          C[(size_t)gm * 256 + (ct0 + ct) * 16 + lm] = (_Float16)acc[rt * 4 + ct][r];
      }
    }
  }
}

// ---------------- helpers ----------------
__device__ inline float2 upk(unsigned u) {
  union { unsigned v; _Float16 h[2]; } c; c.v = u;
  return make_float2((float)c.h[0], (float)c.h[1]);
}
__device__ inline half2t as_h2(unsigned u) {
  union { unsigned v; half2t h; } c; c.v = u;
  return c.h;
}
__device__ inline unsigned as_u32(half2t h) {
  union { half2t h; unsigned v; } c; c.h = h;
  return c.v;
}
__device__ inline unsigned pkadd(unsigned a, unsigned b) {
  return as_u32(as_h2(a) + as_h2(b));   // v_pk_add_f16
}
__device__ inline void pkacc4(uint4& A, const uint4& v) {
  A.x = pkadd(A.x, v.x); A.y = pkadd(A.y, v.y);
  A.z = pkadd(A.z, v.z); A.w = pkadd(A.w, v.w);
}

// ---------------- core gather: 1 node/wave, 16 col-lanes x 4 edge slots --------------
__device__ inline uint4 gather_rows(const unsigned* __restrict__ yzu,
                                    const int* __restrict__ sorted_src,
                                    int start, int end, int cl, int slot) {
  uint4 A0 = make_uint4(0u, 0u, 0u, 0u);
  uint4 A1 = A0;
  int k = start + slot;
  for (; k + 12 < end; k += 16) {
    int s0 = sorted_src[k];
    int s1 = sorted_src[k + 4];
    int s2 = sorted_src[k + 8];
    int s3 = sorted_src[k + 12];
    uint4 v0 = *(const uint4*)(yzu + (size_t)s0 * 128 + cl * 4);
    uint4 v1 = *(const uint4*)(yzu + (size_t)s1 * 128 + cl * 4);
    uint4 v2 = *(const uint4*)(yzu + (size_t)s2 * 128 + cl * 4);
    uint4 v3 = *(const uint4*)(yzu + (size_t)s3 * 128 + cl * 4);
    pkacc4(A0, v0);
    pkacc4(A1, v1);
    pkacc4(A0, v2);
    pkacc4(A1, v3);
  }
  if (k + 4 < end) {   // 2-deep tail
    int s0 = sorted_src[k];
    int s1 = sorted_src[k + 4];
    uint4 v0 = *(const uint4*)(yzu + (size_t)s0 * 128 + cl * 4);
    uint4 v1 = *(const uint4*)(yzu + (size_t)s1 * 128 + cl * 4);
    pkacc4(A0, v0);
    pkacc4(A1, v1);
    k += 8;
  }
  if (k < end) {
    int s = sorted_src[k];
    uint4 v = *(const uint4*)(yzu + (size_t)s * 128 + cl * 4);
    pkacc4(A0, v);
  }
  pkacc4(A0, A1);
#pragma unroll
  for (int off = 16; off < 64; off <<= 1) {
    uint4 o;
    o.x = (unsigned)__shfl_xor((int)A0.x, off, 64);
    o.y = (unsigned)__shfl_xor((int)A0.y, off, 64);
    o.z = (unsigned)__shfl_xor((int)A0.z, off, 64);
    o.w = (unsigned)__shfl_xor((int)A0.w, off, 64);
    pkacc4(A0, o);
  }
  return A0;
}

// ---------------- layer-1 aggregate + combine + ReLU ----------------
__global__ __launch_bounds__(256) void agg_relu16(
    const unsigned* __restrict__ yzu, const int* __restrict__ sorted_src,
    const int* __restrict__ rs, const int* __restrict__ re,
    const float* __restrict__ bias, unsigned* __restrict__ h1u, int N) {
  const int w = threadIdx.x >> 6;
  const int lane = threadIdx.x & 63;
  const int cl = lane & 15;
  const int slot = lane >> 4;
  const int node = blockIdx.x * 4 + w;
  if (node >= N) return;
  const int start = rs[node];
  const int end = re[node];
  uint4 A = gather_rows(yzu, sorted_src, start, end, cl, slot);
  if (slot == 0) {
    const int deg = end - start;
    const float inv = 1.f / (float)max(deg, 1);
    uint4 z4 = *(const uint4*)(yzu + (size_t)node * 128 + 64 + cl * 4);
    const unsigned av[4] = {A.x, A.y, A.z, A.w};
    const unsigned zv[4] = {z4.x, z4.y, z4.z, z4.w};
    uint4 o;
    unsigned ov[4];
#pragma unroll
    for (int q = 0; q < 4; ++q) {
      const int cp = cl * 4 + q;
      float2 a = upk(av[q]);
      float2 z = upk(zv[q]);
      float vx = fmaxf(a.x * inv + bias[2 * cp] + z.x, 0.f);
      float vy = fmaxf(a.y * inv + bias[2 * cp + 1] + z.y, 0.f);
      union { unsigned v; _Float16 h[2]; } c;
      c.h[0] = (_Float16)vx; c.h[1] = (_Float16)vy;
      ov[q] = c.v;
    }
    o.x = ov[0]; o.y = ov[1]; o.z = ov[2]; o.w = ov[3];
    *(uint4*)(h1u + (size_t)node * 64 + cl * 4) = o;
  }
}

// ---------------- layer-2 aggregate + combine + fused scorer projection --------------
__global__ __launch_bounds__(256) void agg_score16(
    const unsigned* __restrict__ yzu, const int* __restrict__ sorted_src,
    const int* __restrict__ rs, const int* __restrict__ re,
    const float* __restrict__ bias, const float* __restrict__ Wlin,
    float* __restrict__ sa, float* __restrict__ sb, int N) {
  const int w = threadIdx.x >> 6;
  const int lane = threadIdx.x & 63;
  const int cl = lane & 15;
  const int slot = lane >> 4;
  const int node = blockIdx.x * 4 + w;
  if (node >= N) return;
  const int start = rs[node];
  const int end = re[node];
  uint4 A = gather_rows(yzu, sorted_src, start, end, cl, slot);
  const int deg = end - start;
  const float inv = 1.f / (float)max(deg, 1);
  uint4 z4 = *(const uint4*)(yzu + (size_t)node * 128 + 64 + cl * 4);
  const unsigned av[4] = {A.x, A.y, A.z, A.w};
  const unsigned zv[4] = {z4.x, z4.y, z4.z, z4.w};
  float pa = 0.f, pb = 0.f;
#pragma unroll
  for (int q = 0; q < 4; ++q) {
    const int cp = cl * 4 + q;
    float2 a = upk(av[q]);
    float2 z = upk(zv[q]);
    float hx = a.x * inv + bias[2 * cp] + z.x;
    float hy = a.y * inv + bias[2 * cp + 1] + z.y;
    pa += hx * Wlin[2 * cp] + hy * Wlin[2 * cp + 1];
    pb += hx * Wlin[128 + 2 * cp] + hy * Wlin[129 + 2 * cp];
  }
#pragma unroll
  for (int off = 1; off < 16; off <<= 1) {
    pa += __shfl_xor(pa, off, 64);
    pb += __shfl_xor(pb, off, 64);
  }
  if (lane == 0) {
    sa[node] = pa;
    sb[node] = pb;
  }
}

// ---------------- edge scoring (both pos and neg in one launch) ----------------
__global__ void score2(const int* __restrict__ pos, const int* __restrict__ neg,
                       int Ep, int En,
                       const float* __restrict__ sa, const float* __restrict__ sb,
                       const float* __restrict__ blin, float* __restrict__ out) {
  int e = blockIdx.x * 256 + threadIdx.x;
  if (e < Ep) {
    out[e] = sa[pos[e]] + sb[pos[Ep + e]] + blin[0];
  } else if (e < Ep + En) {
    int i = e - Ep;
    out[Ep + i] = sa[neg[i]] + sb[neg[En + i]] + blin[0];
  }
}

extern "C" void kernel_launch(void* const* d_in, const int* in_sizes, int n_in,
                              void* d_out, int out_size, void* d_ws, size_t ws_size,
                              hipStream_t stream) {
  (void)n_in; (void)out_size; (void)ws_size;
  const float* x    = (const float*)d_in[0];
  const int*   ei   = (const int*)d_in[1];
  const int*   pos  = (const int*)d_in[2];
  const int*   neg  = (const int*)d_in[3];
  const float* Wl1  = (const float*)d_in[4];
  const float* bl1  = (const float*)d_in[5];
  const float* Wr1  = (const float*)d_in[6];
  const float* Wl2  = (const float*)d_in[7];
  const float* bl2  = (const float*)d_in[8];
  const float* Wr2  = (const float*)d_in[9];
  const float* Wlin = (const float*)d_in[10];
  const float* blin = (const float*)d_in[11];

  const int N  = in_sizes[0] / IN_DIM;  // 100000
  const int E  = in_sizes[1] / 2;       // 3200000
  const int Ep = in_sizes[2] / 2;       // 500000
  const int En = in_sizes[3] / 2;       // 500000
  const int* e_src = ei;
  const int* e_dst = ei + E;

  char* ws = (char*)d_ws;
  size_t off = 0;
  auto carve = [&](size_t bytes) -> char* {
    char* p = ws + off;
    off += (bytes + 255) & ~(size_t)255;
    return p;
  };
  const int nB = (N + NPB - 1) / NPB;   // 391 buckets
  const int KS1 = IN_DIM / 32;          // 12
  const int KS2 = HID / 32;             // 4

  int*      rs     = (int*)carve((size_t)N * 4);
  int*      re     = (int*)carve((size_t)N * 4);
  int*      bCur   = (int*)carve(512 * 4);
  unsigned* bData  = (unsigned*)carve((size_t)nB * BCAP * 4);
  int*      sorted = (int*)carve((size_t)nB * BCAP * 4);
  float*    sa     = (float*)carve((size_t)N * 4);
  float*    sb     = (float*)carve((size_t)N * 4);
  _Float16* Bp1    = (_Float16*)carve((size_t)16 * KS1 * 64 * 8 * 2);
  _Float16* Bp2    = (_Float16*)carve((size_t)16 * KS2 * 64 * 8 * 2);
  _Float16* yz     = (_Float16*)carve((size_t)N * 256 * 2);
  _Float16* h1     = (_Float16*)carve((size_t)N * 128 * 2);

  const int gemmBlocks = (N + 127) / 128;
  const int partBlocks = (E + 8191) / 8192;  // 391

  // CSR build
  hipLaunchKernelGGL(zero_i32, dim3(2), dim3(256), 0, stream, bCur, 512);
  hipLaunchKernelGGL(partition_kernel, dim3(partBlocks), dim3(512), 0, stream,
                     e_src, e_dst, E, nB, bCur, bData);
  hipLaunchKernelGGL(node_sort3, dim3(nB), dim3(1024), LCAP * 4, stream,
                     bData, bCur, N, sorted, rs, re);

  // weight packing
  hipLaunchKernelGGL(pack_w2, dim3(8, KS1, 2), dim3(64), 0, stream, Wl1, Wr1, Bp1);
  hipLaunchKernelGGL(pack_w2, dim3(8, KS2, 2), dim3(64), 0, stream, Wl2, Wr2, Bp2);

  // layer 1
  hipLaunchKernelGGL(gemm_f32a, dim3(gemmBlocks), dim3(512), 0, stream,
                     x, N, Bp1, yz);
  hipLaunchKernelGGL(agg_relu16, dim3((N + 3) / 4), dim3(256), 0, stream,
                     (const unsigned*)yz, sorted, rs, re, bl1, (unsigned*)h1, N);
  // layer 2
  hipLaunchKernelGGL(gemm_f16a, dim3(gemmBlocks), dim3(512), 0, stream,
                     h1, N, Bp2, yz);
  hipLaunchKernelGGL(agg_score16, dim3((N + 3) / 4), dim3(256), 0, stream,
                     (const unsigned*)yz, sorted, rs, re, bl2, Wlin, sa, sb, N);

  // scoring (single launch)
  float* out = (float*)d_out;
  hipLaunchKernelGGL(score2, dim3((Ep + En + 255) / 256), dim3(256), 0, stream,
                     pos, neg, Ep, En, sa, sb, blin, out);
}